// Round 1
// baseline (1061.746 us; speedup 1.0000x reference)
//
#include <hip/hip_runtime.h>
#include <math.h>

#define B_ 128
#define S_ 2048
#define H_ 512
#define V_ 32000
#define NCH 8          // s-chunks per batch for attention
#define NW 4           // waves per block
#define NP (NCH * NW)  // partials per batch = 32

// ---------------------------------------------------------------------------
// Generic tiled fp32 GEMM: C[M,N] = A[M,K] @ B[N,K]^T + bias[N], opt tanh.
// A rows optionally gathered via arows (embedding lookup).
// threads = (BM/TM)*(BN/TN) must equal 256.
// ---------------------------------------------------------------------------
template <int BM, int BN, int BK, int TM, int TN, int ACT>
__global__ __launch_bounds__(256) void gemm_tn(
    const float* __restrict__ A, const int* __restrict__ arows,
    const float* __restrict__ Bm, const float* __restrict__ bias,
    float* __restrict__ C, int M, int N, int K) {
  __shared__ float As[BK][BM + 4];
  __shared__ float Bs[BK][BN + 4];
  const int tid = threadIdx.x;
  const int tx = tid % (BN / TN);
  const int ty = tid / (BN / TN);
  const int n0 = blockIdx.x * BN;
  const int m0 = blockIdx.y * BM;

  float acc[TM][TN];
#pragma unroll
  for (int i = 0; i < TM; i++)
#pragma unroll
    for (int j = 0; j < TN; j++) acc[i][j] = 0.f;

  for (int k0 = 0; k0 < K; k0 += BK) {
#pragma unroll
    for (int e = tid; e < BM * BK; e += 256) {
      int m = e / BK, kk = e % BK;
      int row = arows ? arows[m0 + m] : (m0 + m);
      As[kk][m] = A[(long)row * K + k0 + kk];
    }
#pragma unroll
    for (int e = tid; e < BN * BK; e += 256) {
      int n = e / BK, kk = e % BK;
      Bs[kk][n] = Bm[(long)(n0 + n) * K + k0 + kk];
    }
    __syncthreads();
#pragma unroll
    for (int kk = 0; kk < BK; kk++) {
      float av[TM], bv[TN];
#pragma unroll
      for (int i = 0; i < TM; i++) av[i] = As[kk][ty * TM + i];
#pragma unroll
      for (int j = 0; j < TN; j++) bv[j] = Bs[kk][tx * TN + j];
#pragma unroll
      for (int i = 0; i < TM; i++)
#pragma unroll
        for (int j = 0; j < TN; j++) acc[i][j] = fmaf(av[i], bv[j], acc[i][j]);
    }
    __syncthreads();
  }

#pragma unroll
  for (int i = 0; i < TM; i++) {
    int m = m0 + ty * TM + i;
#pragma unroll
    for (int j = 0; j < TN; j++) {
      int n = n0 + tx * TN + j;
      float c = acc[i][j] + bias[n];
      if (ACT == 1) c = tanhf(c);
      C[(long)m * N + n] = c;
    }
  }
}

// ---------------------------------------------------------------------------
// GRU elementwise: combines gi, gh -> h_new; writes h_new output and the
// left half of the concat input.
// ---------------------------------------------------------------------------
__global__ __launch_bounds__(256) void gru_ew(
    const float* __restrict__ gi, const float* __restrict__ gh,
    const float* __restrict__ hlast, float* __restrict__ hnew,
    float* __restrict__ cin) {
  int idx = blockIdx.x * 256 + threadIdx.x;  // 0..B*H
  int b = idx >> 9, j = idx & 511;
  const float* gib = gi + b * 1536;
  const float* ghb = gh + b * 1536;
  float gir = gib[j], giz = gib[512 + j], gin = gib[1024 + j];
  float ghr = ghb[j], ghz = ghb[512 + j], ghn = ghb[1024 + j];
  float r = 1.f / (1.f + __expf(-(gir + ghr)));
  float z = 1.f / (1.f + __expf(-(giz + ghz)));
  float n = tanhf(gin + r * ghn);
  float h = (1.f - z) * n + z * hlast[idx];
  hnew[idx] = h;
  cin[b * 1024 + j] = h;
}

// ---------------------------------------------------------------------------
// Fused attention pass 1: per (batch, s-chunk) block, each wave streams 64
// s-rows. Computes e_s = h.enc[b,s,:] from float4 regs, does online softmax
// with in-register context accumulation (enc read from HBM exactly once).
// Writes raw energies + per-wave (m, l, acc[512]) partials.
// ---------------------------------------------------------------------------
__global__ __launch_bounds__(256) void attn_partial(
    const float* __restrict__ enc, const float* __restrict__ hnew,
    float* __restrict__ energies, float* __restrict__ pm,
    float* __restrict__ pl, float* __restrict__ pacc) {
  const int bid = blockIdx.x;
  const int b = bid >> 3;  // / NCH
  const int c = bid & (NCH - 1);
  const int wave = threadIdx.x >> 6;
  const int lane = threadIdx.x & 63;

  const float4* hp = (const float4*)(hnew + b * H_);
  const float4 hA = hp[lane];       // floats [lane*4, lane*4+4)
  const float4 hB = hp[64 + lane];  // floats [256+lane*4, ...)

  float m = -INFINITY, l = 0.f;
  float4 aA = {0.f, 0.f, 0.f, 0.f}, aB = {0.f, 0.f, 0.f, 0.f};
  float my_e = 0.f;
  const int s0 = c * 256 + wave * 64;

#pragma unroll 2
  for (int i = 0; i < 64; ++i) {
    int s = s0 + i;
    const float4* ep = (const float4*)(enc + ((long)b * S_ + s) * H_);
    float4 eA = ep[lane];
    float4 eB = ep[64 + lane];
    float v = eA.x * hA.x + eA.y * hA.y + eA.z * hA.z + eA.w * hA.w +
              eB.x * hB.x + eB.y * hB.y + eB.z * hB.z + eB.w * hB.w;
#pragma unroll
    for (int off = 32; off > 0; off >>= 1) v += __shfl_xor(v, off);
    if (lane == i) my_e = v;  // stash for coalesced energies store
    float mn = fmaxf(m, v);
    float sc = __expf(m - mn);  // first iter: exp(-inf)=0
    float p = __expf(v - mn);
    m = mn;
    l = l * sc + p;
    aA.x = aA.x * sc + p * eA.x;
    aA.y = aA.y * sc + p * eA.y;
    aA.z = aA.z * sc + p * eA.z;
    aA.w = aA.w * sc + p * eA.w;
    aB.x = aB.x * sc + p * eB.x;
    aB.y = aB.y * sc + p * eB.y;
    aB.z = aB.z * sc + p * eB.z;
    aB.w = aB.w * sc + p * eB.w;
  }

  energies[(long)b * S_ + s0 + lane] = my_e;
  int pidx = b * NP + c * NW + wave;
  if (lane == 0) {
    pm[pidx] = m;
    pl[pidx] = l;
  }
  float4* pa = (float4*)(pacc + (long)pidx * H_);
  pa[lane] = aA;
  pa[64 + lane] = aB;
}

// ---------------------------------------------------------------------------
// Attention pass 2: merge 32 partials per batch -> global (m, l); emit
// context into right half of concat input, and normalized attn weights.
// ---------------------------------------------------------------------------
__global__ __launch_bounds__(256) void attn_combine(
    const float* __restrict__ energies, const float* __restrict__ pm,
    const float* __restrict__ pl, const float* __restrict__ pacc,
    float* __restrict__ attn, float* __restrict__ cin) {
  const int b = blockIdx.x;
  const int tid = threadIdx.x;

  float m_b = -INFINITY;
#pragma unroll
  for (int i = 0; i < NP; i++) m_b = fmaxf(m_b, pm[b * NP + i]);
  float wgt[NP];
  float l_b = 0.f;
#pragma unroll
  for (int i = 0; i < NP; i++) {
    wgt[i] = __expf(pm[b * NP + i] - m_b);
    l_b += pl[b * NP + i] * wgt[i];
  }
  float inv = 1.f / l_b;

  for (int k = tid; k < H_; k += 256) {
    float s = 0.f;
#pragma unroll
    for (int i = 0; i < NP; i++)
      s += pacc[(long)(b * NP + i) * H_ + k] * wgt[i];
    cin[b * 1024 + 512 + k] = s * inv;
  }
  for (int s = tid; s < S_; s += 256) {
    attn[(long)b * S_ + s] = __expf(energies[(long)b * S_ + s] - m_b) * inv;
  }
}

// ---------------------------------------------------------------------------
extern "C" void kernel_launch(void* const* d_in, const int* in_sizes, int n_in,
                              void* d_out, int out_size, void* d_ws,
                              size_t ws_size, hipStream_t stream) {
  const int* idx = (const int*)d_in[0];
  const float* hlast = (const float*)d_in[1];   // (B,1,H)
  const float* enc = (const float*)d_in[2];     // (B,S,H)
  const float* emb = (const float*)d_in[3];     // (V,H)
  const float* w_ih = (const float*)d_in[4];    // (3H,H)
  const float* w_hh = (const float*)d_in[5];    // (3H,H)
  const float* b_ih = (const float*)d_in[6];
  const float* b_hh = (const float*)d_in[7];
  const float* W_cat = (const float*)d_in[8];   // (H,2H)
  const float* b_cat = (const float*)d_in[9];
  const float* W_out = (const float*)d_in[10];  // (V,H)
  const float* b_out = (const float*)d_in[11];

  float* out = (float*)d_out;                 // (B,V)
  float* out_h = out + (long)B_ * V_;         // (B,1,H)
  float* out_a = out_h + B_ * H_;             // (B,S,1)

  float* ws = (float*)d_ws;
  float* gi = ws;                              // B*3H
  float* gh = gi + B_ * 3 * H_;                // B*3H
  float* en = gh + B_ * 3 * H_;                // B*S
  float* pm = en + (long)B_ * S_;              // B*NP
  float* pl = pm + B_ * NP;                    // B*NP
  float* pacc = pl + B_ * NP;                  // B*NP*H
  float* cin = pacc + (long)B_ * NP * H_;      // B*2H
  float* cout = cin + B_ * 2 * H_;             // B*H

  dim3 blk(256);
  // GRU gate GEMMs: M=128, N=1536, K=512
  gemm_tn<32, 32, 16, 2, 2, 0><<<dim3(1536 / 32, 128 / 32), blk, 0, stream>>>(
      emb, idx, w_ih, b_ih, gi, B_, 3 * H_, H_);
  gemm_tn<32, 32, 16, 2, 2, 0><<<dim3(1536 / 32, 128 / 32), blk, 0, stream>>>(
      hlast, nullptr, w_hh, b_hh, gh, B_, 3 * H_, H_);
  gru_ew<<<dim3(B_ * H_ / 256), blk, 0, stream>>>(gi, gh, hlast, out_h, cin);
  // Fused single-pass attention
  attn_partial<<<dim3(B_ * NCH), blk, 0, stream>>>(enc, out_h, en, pm, pl,
                                                   pacc);
  attn_combine<<<dim3(B_), blk, 0, stream>>>(en, pm, pl, pacc, out_a, cin);
  // concat GEMM: M=128, N=512, K=1024, tanh
  gemm_tn<32, 32, 16, 2, 2, 1><<<dim3(512 / 32, 128 / 32), blk, 0, stream>>>(
      cin, nullptr, W_cat, b_cat, cout, B_, H_, 2 * H_);
  // output GEMM: M=128, N=32000, K=512
  gemm_tn<128, 64, 16, 8, 4, 0><<<dim3(V_ / 64, 1), blk, 0, stream>>>(
      cout, nullptr, W_out, b_out, out, B_, V_, H_);
}